// Round 5
// baseline (153.176 us; speedup 1.0000x reference)
//
#include <hip/hip_runtime.h>

#define NB 8
#define NT 400
#define NN 200
#define ND 80
#define NROWS (NB * NT * NN)
#define PROD_BLOCKS (NROWS / 64)

typedef unsigned long long u64;

static constexpr float BIG_NEG = -1e30f;
static constexpr float LN2 = 0.6931471805599453f;
static constexpr float LOG2E = 1.4426950408889634f;
static constexpr float L2EPS = -99.65784284662087f;        // log(1e-30)*LOG2E
static constexpr float HALF_LOG2E = 0.7213475204444817f;   // 0.5*LOG2E
static constexpr float D_HALF_L2PI = 106.05984517680935f;  // D*0.5*log(2pi)*LOG2E

#define A_LD(p) __hip_atomic_load((p), __ATOMIC_RELAXED, __HIP_MEMORY_SCOPE_AGENT)
#define A_ST(p, v) __hip_atomic_store((p), (v), __ATOMIC_RELAXED, __HIP_MEMORY_SCOPE_AGENT)

static __device__ __forceinline__ float hw_exp2(float x) { return __builtin_amdgcn_exp2f(x); }
static __device__ __forceinline__ float hw_log2(float x) { return __builtin_amdgcn_logf(x); }

// log2(2^a + 2^b); a,b possibly ~ -1e30
static __device__ __forceinline__ float l2add(float a, float b) {
    float mx = fmaxf(a, b);
    float d = fminf(a, b) - mx;  // <= 0
    return mx + hw_log2(1.0f + hw_exp2(d));
}

// log2(1 + 2^-|w|), in [0,1]
static __device__ __forceinline__ float softplus2(float w) {
    return hw_log2(1.0f + hw_exp2(-fabsf(w)));
}

// whole-wave shift right by 1 lane via DPP; lane 0 receives `fill`
static __device__ __forceinline__ float wave_shr1(float x, float fill) {
    int r = __builtin_amdgcn_update_dpp(__float_as_int(fill), __float_as_int(x),
                                        0x138 /*wave_shr:1*/, 0xF, 0xF, false);
    return __int_as_float(r);
}

// ---------------------------------------------------------------------------
// Fused kernel. Blocks 0..7: scanner (one wave per b). Blocks 8..: producers.
// Producers: emission+transition fold -> SE/ME (agent-scope stores), then one
// atomicAdd per (b,t) group touched (release via syncthreads store drain).
// Scanners: spin on per-(b,t) row-completion flags (pipelined 1 window ahead),
// read SE/ME with agent-scope u64 loads, depth-16 register pipeline.
// ---------------------------------------------------------------------------
__global__ __launch_bounds__(256) void fused_kernel(
    const float* __restrict__ mels,   // (B,T,D)
    const float* __restrict__ means,  // (B,T,N,D)
    const float* __restrict__ stds,   // (B,T,N,D)
    const float* __restrict__ tv,     // (B,T,N)
    const int* __restrict__ inputs_len,
    const int* __restrict__ mel_lens,
    float* __restrict__ SE,           // (B,T,N) ws
    float* __restrict__ ME,           // (B,T,N) ws
    unsigned* __restrict__ flags,     // (B,T) ws, pre-zeroed
    float* __restrict__ out)          // (B,)
{
    if (blockIdx.x >= NB) {
        // ----------------------------- producer -----------------------------
        const int bp = blockIdx.x - NB;
        const int tid = threadIdx.x;
        const int R = bp * 64 + (tid >> 2);
        const int q = tid & 3;
        const int b = R / (NT * NN);
        const int r2 = R - b * (NT * NN);
        const int t = r2 / NN;
        const int n = r2 - t * NN;
        const int ml = mel_lens[b];
        const int il = inputs_len[b];

        if (t < ml) {
            if (n >= il) {
                if (q == 0) { A_ST(&SE[R], BIG_NEG); A_ST(&ME[R], BIG_NEG); }
            } else {
                const float4* mp = reinterpret_cast<const float4*>(means) + (size_t)R * (ND / 4) + q;
                const float4* sp = reinterpret_cast<const float4*>(stds)  + (size_t)R * (ND / 4) + q;
                const float4* xp = reinterpret_cast<const float4*>(mels)  + (size_t)(b * NT + t) * (ND / 4) + q;
                float acc = 0.f;
#pragma unroll
                for (int k = 0; k < ND / 16; ++k) {
                    const float4 m = mp[k * 4];
                    const float4 s = sp[k * 4];
                    const float4 x = xp[k * 4];
                    float z0 = __fdividef(x.x - m.x, s.x);
                    float z1 = __fdividef(x.y - m.y, s.y);
                    float z2 = __fdividef(x.z - m.z, s.z);
                    float z3 = __fdividef(x.w - m.w, s.w);
                    acc += fmaf(z0 * HALF_LOG2E, z0, hw_log2(s.x));
                    acc += fmaf(z1 * HALF_LOG2E, z1, hw_log2(s.y));
                    acc += fmaf(z2 * HALF_LOG2E, z2, hw_log2(s.z));
                    acc += fmaf(z3 * HALF_LOG2E, z3, hw_log2(s.w));
                }
                acc += __shfl_xor(acc, 1);
                acc += __shfl_xor(acc, 2);
                if (q == 0) {
                    const float e2 = -acc - D_HALF_L2PI;
                    if (t == 0) {
                        A_ST(&SE[R], e2);
                        A_ST(&ME[R], BIG_NEG);
                    } else {
                        const size_t base = (size_t)b * NT * NN + (size_t)t * NN;
                        float w = tv[base + n] * LOG2E;
                        float stay2 = -(fmaxf(w, 0.f) + softplus2(w));
                        A_ST(&SE[R], e2 + fmaxf(stay2, L2EPS));
                        if (n == 0) {
                            A_ST(&ME[R], BIG_NEG);
                        } else {
                            float u = tv[base + n - 1] * LOG2E;
                            float mv2 = -(fmaxf(-u, 0.f) + softplus2(u));
                            A_ST(&ME[R], e2 + fmaxf(mv2, L2EPS));
                        }
                    }
                }
            }
        }
        __syncthreads();  // drains each wave's stores (vmcnt 0) before signal
        if (tid == 0) {
            const int R0 = bp * 64;
            const int g0 = R0 / NN, g1 = (R0 + 63) / NN;
            if (g0 == g1) {
                atomicAdd(&flags[g0], 64u);
            } else {
                unsigned c0 = (unsigned)((g0 + 1) * NN - R0);
                atomicAdd(&flags[g0], c0);
                atomicAdd(&flags[g1], 64u - c0);
            }
        }
        return;
    }

    // ------------------------------- scanner --------------------------------
    const int b = blockIdx.x;
    if (threadIdx.x >= 64) return;
    const int lane = threadIdx.x;
    const int il = inputs_len[b];
    const int ml = mel_lens[b];
    const int mlm1 = ml - 1;
    const int cl = (lane < NN / 4) ? lane : (NN / 4 - 1);

    float* seb = SE + (size_t)b * NT * NN;
    float* meb = ME + (size_t)b * NT * NN;
    const float* vb = tv + (size_t)b * NT * NN;
    unsigned* flg = flags + b * NT;
    u64* se64 = reinterpret_cast<u64*>(seb);
    u64* me64 = reinterpret_cast<u64*>(meb);

    unsigned fv0, fv1, fv2, fv3, fv4, fv5, fv6, fv7;
    unsigned fv8, fv9, fv10, fv11, fv12, fv13, fv14, fv15;
#define FLD(K, TT) fv##K = ((TT) < ml) ? A_LD(flg + (TT)) : (unsigned)NN;
#define FCHK(K, TT) if ((TT) < ml) { while (fv##K < (unsigned)NN) fv##K = A_LD(flg + (TT)); }
#define F16(OP, TT0) OP(0,(TT0)) OP(1,(TT0)+1) OP(2,(TT0)+2) OP(3,(TT0)+3) \
    OP(4,(TT0)+4) OP(5,(TT0)+5) OP(6,(TT0)+6) OP(7,(TT0)+7) \
    OP(8,(TT0)+8) OP(9,(TT0)+9) OP(10,(TT0)+10) OP(11,(TT0)+11) \
    OP(12,(TT0)+12) OP(13,(TT0)+13) OP(14,(TT0)+14) OP(15,(TT0)+15)

    // confirm t in [0,17)
    F16(FLD, 0)
    F16(FCHK, 0)
    FLD(0, 16) FCHK(0, 16)
    // flag pipeline: fv <- flags[17..33)
    F16(FLD, 17)
    asm volatile("" ::: "memory");

    // data slots (depth 16): slot S holds t = base+S; each slot = 4 x u64
    u64 sa0,sb0,ma0,mb0, sa1,sb1,ma1,mb1, sa2,sb2,ma2,mb2, sa3,sb3,ma3,mb3;
    u64 sa4,sb4,ma4,mb4, sa5,sb5,ma5,mb5, sa6,sb6,ma6,mb6, sa7,sb7,ma7,mb7;
    u64 sa8,sb8,ma8,mb8, sa9,sb9,ma9,mb9, sa10,sb10,ma10,mb10, sa11,sb11,ma11,mb11;
    u64 sa12,sb12,ma12,mb12, sa13,sb13,ma13,mb13, sa14,sb14,ma14,mb14, sa15,sb15,ma15,mb15;

#define LDSLOT(S, TT) { \
        int tn_ = ((TT) <= mlm1) ? (TT) : mlm1; \
        size_t o_ = (size_t)tn_ * (NN / 2) + (cl << 1); \
        sa##S = A_LD(se64 + o_); sb##S = A_LD(se64 + o_ + 1); \
        ma##S = A_LD(me64 + o_); mb##S = A_LD(me64 + o_ + 1); }

#define SLOT16(OP, TT0) OP(0,(TT0)) OP(1,(TT0)+1) OP(2,(TT0)+2) OP(3,(TT0)+3) \
    OP(4,(TT0)+4) OP(5,(TT0)+5) OP(6,(TT0)+6) OP(7,(TT0)+7) \
    OP(8,(TT0)+8) OP(9,(TT0)+9) OP(10,(TT0)+10) OP(11,(TT0)+11) \
    OP(12,(TT0)+12) OP(13,(TT0)+13) OP(14,(TT0)+14) OP(15,(TT0)+15)

    // preload slots for t = 1..16
    SLOT16(LDSLOT, 1)

    // init: t=0, only state 0 finite (prior); SE[b][0][0] holds raw e2
    float la0 = (lane == 0) ? A_LD(seb) : BIG_NEG;
    float la1 = BIG_NEG, la2 = BIG_NEG, la3 = BIG_NEG;

#define STEPBODY(S) \
        float2 sxy = __builtin_bit_cast(float2, sa##S); \
        float2 szw = __builtin_bit_cast(float2, sb##S); \
        float2 mxy = __builtin_bit_cast(float2, ma##S); \
        float2 mzw = __builtin_bit_cast(float2, mb##S); \
        float carry = wave_shr1(la3, BIG_NEG); \
        float a0 = la0 + sxy.x, c0 = carry + mxy.x; \
        float a1 = la1 + sxy.y, c1 = la0 + mxy.y; \
        float a2 = la2 + szw.x, c2 = la1 + mzw.x; \
        float a3 = la3 + szw.y, c3 = la2 + mzw.y; \
        la0 = l2add(a0, c0); la1 = l2add(a1, c1); \
        la2 = l2add(a2, c2); la3 = l2add(a3, c3);

#define STEP(S, TT) { \
        float2 sxy = __builtin_bit_cast(float2, sa##S); \
        float2 szw = __builtin_bit_cast(float2, sb##S); \
        float2 mxy = __builtin_bit_cast(float2, ma##S); \
        float2 mzw = __builtin_bit_cast(float2, mb##S); \
        LDSLOT(S, (TT) + 16) \
        float carry = wave_shr1(la3, BIG_NEG); \
        float a0 = la0 + sxy.x, c0 = carry + mxy.x; \
        float a1 = la1 + sxy.y, c1 = la0 + mxy.y; \
        float a2 = la2 + szw.x, c2 = la1 + mzw.x; \
        float a3 = la3 + szw.y, c3 = la2 + mzw.y; \
        la0 = l2add(a0, c0); la1 = l2add(a1, c1); \
        la2 = l2add(a2, c2); la3 = l2add(a3, c3); }

#define TSTEP(S, K) if (t + (K) < ml) { STEPBODY(S) }

    int t = 1;
    for (; t + 15 < ml; t += 16) {
        // flags [t+16, t+32) were loaded one iteration ago -> verify
        F16(FCHK, t + 16)
        asm volatile("" ::: "memory");
        // issue next window's flag loads [t+32, t+48)
        F16(FLD, t + 32)
        // 16 steps; each consumes slot S (= data t+S) and reloads t+S+16
        SLOT16(STEP, t)
    }
    // tail (<16 steps): slots hold t..t+15, already confirmed
    {
        TSTEP(0, 0)  TSTEP(1, 1)  TSTEP(2, 2)  TSTEP(3, 3)
        TSTEP(4, 4)  TSTEP(5, 5)  TSTEP(6, 6)  TSTEP(7, 7)
        TSTEP(8, 8)  TSTEP(9, 9)  TSTEP(10, 10) TSTEP(11, 11)
        TSTEP(12, 12) TSTEP(13, 13) TSTEP(14, 14) TSTEP(15, 15)
    }

    // final: only state il-1 contributes
    const int fin = il - 1;
    const int n0 = lane * 4;
    if (fin >= n0 && fin < n0 + 4) {
        float w = vb[(size_t)mlm1 * NN + fin] * LOG2E;
        float lmove2 = fmaxf(-(fmaxf(-w, 0.f) + softplus2(w)), L2EPS);
        float lastla = (fin == n0)     ? la0
                     : (fin == n0 + 1) ? la1
                     : (fin == n0 + 2) ? la2
                                       : la3;
        out[b] = LN2 * (lastla + lmove2);
    }
#undef FLD
#undef FCHK
#undef F16
#undef LDSLOT
#undef SLOT16
#undef STEPBODY
#undef STEP
#undef TSTEP
}

extern "C" void kernel_launch(void* const* d_in, const int* in_sizes, int n_in,
                              void* d_out, int out_size, void* d_ws, size_t ws_size,
                              hipStream_t stream) {
    const float* mels  = (const float*)d_in[0];
    const float* means = (const float*)d_in[1];
    const float* stds  = (const float*)d_in[2];
    const float* tv    = (const float*)d_in[3];
    const int* inputs_len = (const int*)d_in[4];
    const int* mel_lens   = (const int*)d_in[5];
    float* out = (float*)d_out;

    float* SE = (float*)d_ws;                       // B*T*N floats
    float* ME = SE + (size_t)NROWS;                 // B*T*N floats
    unsigned* flags = (unsigned*)(ME + (size_t)NROWS);  // B*T uints

    hipMemsetAsync(flags, 0, (size_t)NB * NT * sizeof(unsigned), stream);
    fused_kernel<<<dim3(PROD_BLOCKS + NB), dim3(256), 0, stream>>>(
        mels, means, stds, tv, inputs_len, mel_lens, SE, ME, flags, out);
}

// Round 6
// 79.477 us; speedup vs baseline: 1.9273x; 1.9273x over previous
//
#include <hip/hip_runtime.h>

#define NB 8
#define NT 400
#define NN 200
#define ND 80

static constexpr float BIG_NEG = -1e30f;
static constexpr float LN2 = 0.6931471805599453f;
static constexpr float LOG2E = 1.4426950408889634f;
static constexpr float L2EPS = -99.65784284662087f;        // log(1e-30)*LOG2E
static constexpr float HALF_LOG2E = 0.7213475204444817f;   // 0.5*LOG2E
static constexpr float D_HALF_L2PI = 106.05984517680935f;  // D*0.5*log2(2pi)

static __device__ __forceinline__ float hw_exp2(float x) { return __builtin_amdgcn_exp2f(x); }
static __device__ __forceinline__ float hw_log2(float x) { return __builtin_amdgcn_logf(x); }

// log2(2^a + 2^b); a,b possibly ~ -1e30
static __device__ __forceinline__ float l2add(float a, float b) {
    float mx = fmaxf(a, b);
    float d = fminf(a, b) - mx;  // <= 0
    return mx + hw_log2(1.0f + hw_exp2(d));
}

// log2(1 + 2^-|w|), in [0,1]
static __device__ __forceinline__ float softplus2(float w) {
    return hw_log2(1.0f + hw_exp2(-fabsf(w)));
}

// whole-wave shift right by 1 lane via DPP; lane 0 receives `fill`
static __device__ __forceinline__ float wave_shr1(float x, float fill) {
    int r = __builtin_amdgcn_update_dpp(__float_as_int(fill), __float_as_int(x),
                                        0x138 /*wave_shr:1*/, 0xF, 0xF, false);
    return __int_as_float(r);
}

// ---------------------------------------------------------------------------
// Kernel 1 (log2 domain): e2 = LOG2E * emission.
//   SE[t][n] = e2 + log2(sigmoid(-tv[t][n]))      (stay)
//   ME[t][n] = e2 + log2(sigmoid( tv[t][n-1]))    (move, pre-shifted)
// log2(std) summed as log2(prod(std)) -- one v_log_f32 per lane (20 elems).
// ---------------------------------------------------------------------------
__global__ __launch_bounds__(256) void emission_kernel(
    const float* __restrict__ mels,   // (B,T,D)
    const float* __restrict__ means,  // (B,T,N,D)
    const float* __restrict__ stds,   // (B,T,N,D)
    const float* __restrict__ tv,     // (B,T,N)
    const int* __restrict__ inputs_len,
    const int* __restrict__ mel_lens,
    float* __restrict__ SE,           // (B,T,N) workspace
    float* __restrict__ ME)           // (B,T,N) workspace
{
    const int tid = threadIdx.x;
    const int R = blockIdx.x * 64 + (tid >> 2);  // row in [0, B*T*N)
    const int q = tid & 3;
    const int b = R / (NT * NN);
    const int r2 = R - b * (NT * NN);
    const int t = r2 / NN;
    const int n = r2 - t * NN;

    if (t >= mel_lens[b]) return;
    if (n >= inputs_len[b]) {
        if (q == 0) { SE[R] = BIG_NEG; ME[R] = BIG_NEG; }
        return;
    }

    const float4* mp = reinterpret_cast<const float4*>(means) + (size_t)R * (ND / 4) + q;
    const float4* sp = reinterpret_cast<const float4*>(stds)  + (size_t)R * (ND / 4) + q;
    const float4* xp = reinterpret_cast<const float4*>(mels)  + (size_t)(b * NT + t) * (ND / 4) + q;

    // acc = sum(HALF_LOG2E*z^2); prod = prod(s); e2 = -(acc+log2(prod)) - D_HALF_L2PI
    float acc = 0.f;
    float prod = 1.f;
#pragma unroll
    for (int k = 0; k < ND / 16; ++k) {
        const float4 m = mp[k * 4];
        const float4 s = sp[k * 4];
        const float4 x = xp[k * 4];
        float z0 = __fdividef(x.x - m.x, s.x);
        float z1 = __fdividef(x.y - m.y, s.y);
        float z2 = __fdividef(x.z - m.z, s.z);
        float z3 = __fdividef(x.w - m.w, s.w);
        acc = fmaf(z0 * HALF_LOG2E, z0, acc);
        acc = fmaf(z1 * HALF_LOG2E, z1, acc);
        acc = fmaf(z2 * HALF_LOG2E, z2, acc);
        acc = fmaf(z3 * HALF_LOG2E, z3, acc);
        prod *= s.x * s.y * s.z * s.w;
    }
    acc += hw_log2(prod);            // prod of 20 stds in [9.5e-7, 3325]: safe
    acc += __shfl_xor(acc, 1);
    acc += __shfl_xor(acc, 2);

    if (q == 0) {
        const float e2 = -acc - D_HALF_L2PI;
        if (t == 0) {
            SE[R] = e2;              // raw (log2-scaled) emission; only n==0 used
            ME[R] = BIG_NEG;
        } else {
            const size_t base = (size_t)b * NT * NN + (size_t)t * NN;
            float w = tv[base + n] * LOG2E;
            float stay2 = -(fmaxf(w, 0.f) + softplus2(w));     // log2 sigmoid(-v)
            SE[R] = e2 + fmaxf(stay2, L2EPS);
            if (n == 0) {
                ME[R] = BIG_NEG;
            } else {
                float u = tv[base + n - 1] * LOG2E;
                float mv2 = -(fmaxf(-u, 0.f) + softplus2(u));  // log2 sigmoid(v)
                ME[R] = e2 + fmaxf(mv2, L2EPS);
            }
        }
    }
}

// ---------------------------------------------------------------------------
// Kernel 2: unnormalized forward recursion in log2 domain, prefetch depth 16.
//   la[n] <- l2add(la[n] + SE[t][n], la[n-1] + ME[t][n])
// One wave per b; lane l holds states 4l..4l+3; DPP wave_shr for the carry.
// 16 statically-named float4 slot pairs (~150 VGPR; 8 waves total, no
// occupancy concern). Slot S holds t with t%16==S; main loop starts t=1,
// steps 16, so t%16==1 at loop head and in the tail.
// ---------------------------------------------------------------------------
__global__ __launch_bounds__(64) void scan_kernel(
    const float* __restrict__ SE,     // (B,T,N)
    const float* __restrict__ ME,     // (B,T,N)
    const float* __restrict__ tv,     // (B,T,N)
    const int* __restrict__ inputs_len,
    const int* __restrict__ mel_lens,
    float* __restrict__ out)          // (B,)
{
    const int b = blockIdx.x;
    const int lane = threadIdx.x;
    const int il = inputs_len[b];
    const int ml = mel_lens[b];
    const int mlm1 = ml - 1;
    const int cl = (lane < NN / 4) ? lane : (NN / 4 - 1);  // clamp: loads in-bounds

    const float* seb = SE + (size_t)b * NT * NN;
    const float* meb = ME + (size_t)b * NT * NN;
    const float* vb  = tv + (size_t)b * NT * NN;

    float la0 = (lane == 0) ? seb[0] : BIG_NEG;
    float la1 = BIG_NEG, la2 = BIG_NEG, la3 = BIG_NEG;

    auto ld4 = [cl](const float* p) { return reinterpret_cast<const float4*>(p)[cl]; };
#define LDT(TT) ((size_t)(((TT) <= mlm1) ? (TT) : mlm1) * NN)

// ordered S = 1..15,0 so OP(S, t) pairs slot S with time TT, TT%16==S
#define SLOT16(OP, T0) \
    OP(1,(T0))     OP(2,(T0)+1)  OP(3,(T0)+2)  OP(4,(T0)+3)  \
    OP(5,(T0)+4)  OP(6,(T0)+5)  OP(7,(T0)+6)  OP(8,(T0)+7)  \
    OP(9,(T0)+8)  OP(10,(T0)+9) OP(11,(T0)+10) OP(12,(T0)+11) \
    OP(13,(T0)+12) OP(14,(T0)+13) OP(15,(T0)+14) OP(0,(T0)+15)

#define PRELOAD(S, TT) \
    float4 se##S = ld4(seb + LDT(TT)); \
    float4 me##S = ld4(meb + LDT(TT));
    // preload t = 1..16 (ml >= 200 so always valid times)
    SLOT16(PRELOAD, 1)
#undef PRELOAD

#define STEPBODY(SEV, MEV) { \
        float carry = wave_shr1(la3, BIG_NEG); \
        float a0 = la0 + SEV.x, c0 = carry + MEV.x; \
        float a1 = la1 + SEV.y, c1 = la0 + MEV.y; \
        float a2 = la2 + SEV.z, c2 = la1 + MEV.z; \
        float a3 = la3 + SEV.w, c3 = la2 + MEV.w; \
        la0 = l2add(a0, c0); la1 = l2add(a1, c1); \
        la2 = l2add(a2, c2); la3 = l2add(a3, c3); }

#define STEP(S, TT) { \
        float4 se_ = se##S, me_ = me##S; \
        se##S = ld4(seb + LDT((TT) + 16)); \
        me##S = ld4(meb + LDT((TT) + 16)); \
        STEPBODY(se_, me_) }

#define TSTEP(S, TT) if ((TT) < ml) { STEPBODY(se##S, me##S) }

    int t = 1;
    for (; t + 15 < ml; t += 16) {
        SLOT16(STEP, t)
    }
    SLOT16(TSTEP, t)   // tail: <= 15 remaining steps, slots hold t..t+15

#undef SLOT16
#undef PRELOAD
#undef STEP
#undef TSTEP
#undef STEPBODY
#undef LDT

    // final: only state il-1 contributes
    const int fin = il - 1;
    const int n0 = lane * 4;
    if (fin >= n0 && fin < n0 + 4) {
        float w = vb[(size_t)mlm1 * NN + fin] * LOG2E;
        float lmove2 = fmaxf(-(fmaxf(-w, 0.f) + softplus2(w)), L2EPS);
        float lastla = (fin == n0)     ? la0
                     : (fin == n0 + 1) ? la1
                     : (fin == n0 + 2) ? la2
                                       : la3;
        out[b] = LN2 * (lastla + lmove2);
    }
}

extern "C" void kernel_launch(void* const* d_in, const int* in_sizes, int n_in,
                              void* d_out, int out_size, void* d_ws, size_t ws_size,
                              hipStream_t stream) {
    const float* mels  = (const float*)d_in[0];
    const float* means = (const float*)d_in[1];
    const float* stds  = (const float*)d_in[2];
    const float* tv    = (const float*)d_in[3];
    const int* inputs_len = (const int*)d_in[4];
    const int* mel_lens   = (const int*)d_in[5];
    float* out = (float*)d_out;

    float* SE = (float*)d_ws;                    // B*T*N floats = 2.56 MB
    float* ME = SE + (size_t)NB * NT * NN;       // B*T*N floats = 2.56 MB

    const int rows = NB * NT * NN;               // 640000
    emission_kernel<<<dim3(rows / 64), dim3(256), 0, stream>>>(
        mels, means, stds, tv, inputs_len, mel_lens, SE, ME);
    scan_kernel<<<dim3(NB), dim3(64), 0, stream>>>(
        SE, ME, tv, inputs_len, mel_lens, out);
}